// Round 1
// baseline (225.308 us; speedup 1.0000x reference)
//
#include <hip/hip_runtime.h>
#include <hip/hip_bf16.h>

#define BT_TOTAL 1024
#define N_AG 64
#define N_OBS 128
#define N_H1 512
#define N_H2 512
#define N_D  256
#define N_K  16

typedef __bf16 bf16x8 __attribute__((ext_vector_type(8)));
typedef float  f32x4  __attribute__((ext_vector_type(4)));
typedef int    i32x4  __attribute__((ext_vector_type(4)));

__device__ inline unsigned short f2bf(float f) {
    unsigned int u = __builtin_bit_cast(unsigned int, f);
    u = (u + 0x7FFFu + ((u >> 16) & 1u)) >> 16;
    return (unsigned short)u;
}

__device__ inline bf16x8 load_bf8_lds(const unsigned short* p) {
    i32x4 t = *(const i32x4*)p;
    return __builtin_bit_cast(bf16x8, t);
}

// -------- weight transpose + bf16 convert: src [K][N] f32 -> dst [N][K] bf16
__global__ void transpose_bf16_kernel(const float* __restrict__ src,
                                      unsigned short* __restrict__ dst,
                                      int K, int N, int tiles_x) {
    __shared__ float tile[32][33];
    int bi = blockIdx.x;
    int tx = bi % tiles_x, ty = bi / tiles_x;
    int k0 = ty * 32, n0 = tx * 32;
    int t = threadIdx.x;
    int c = t & 31, r0 = t >> 5;
#pragma unroll
    for (int i = 0; i < 4; ++i) {
        int r = r0 + i * 8;
        tile[r][c] = src[(size_t)(k0 + r) * N + n0 + c];
    }
    __syncthreads();
#pragma unroll
    for (int i = 0; i < 4; ++i) {
        int rr = r0 + i * 8;
        dst[(size_t)(n0 + rr) * K + k0 + c] = f2bf(tile[c][rr]);
    }
}

// LDS layout (bytes):
//   hA   @ 0      : [64][520] ushort (h1 bf16)          = 66560
//        later embF [64][260] f32 (same 66560 bytes)
//   hB   @ 66560  : [64][520] ushort (h2 bf16)          = 66560
//        later: qF [16][260] f32 @ +0      (16640)
//               s1 [16][65]  f32 @ +16640  (4160)
//               s2 [64][17]  f32 @ +20800  (4352)
//               mk [64]      i32 @ +25152  (256)
//             tokF [16][260] f32 @ +25408  (16640)
// total = 133120 bytes
#define LDS_BYTES 133120

__global__ __launch_bounds__(512, 1) void fused_mlp_attn(
    const float* __restrict__ obs, const int* __restrict__ amask,
    const unsigned short* __restrict__ WT1, const float* __restrict__ b1,
    const unsigned short* __restrict__ WT2, const float* __restrict__ b2,
    const unsigned short* __restrict__ WT3, const float* __restrict__ b3,
    const float* __restrict__ tq,
    float* __restrict__ outT, float* __restrict__ outC)
{
    extern __shared__ __align__(16) char smem[];
    unsigned short* hA = (unsigned short*)smem;             // [64][520]
    unsigned short* hB = (unsigned short*)(smem + 66560);   // [64][520]
    float* embF = (float*)smem;                             // [64][260]
    float* qF   = (float*)(smem + 66560);                   // [16][260]
    float* s1   = (float*)(smem + 66560 + 16640);           // [16][65]
    float* s2   = (float*)(smem + 66560 + 20800);           // [64][17]
    int*   mk   = (int*)  (smem + 66560 + 25152);           // [64]
    float* tokF = (float*)(smem + 66560 + 25408);           // [16][260]

    const int bt   = blockIdx.x;
    const int tid  = threadIdx.x;
    const int lane = tid & 63;
    const int wave = tid >> 6;
    const int l16  = lane & 15;
    const int l4   = lane >> 4;

    const float* obsG = obs + (size_t)bt * (N_AG * N_OBS);

    // ================= Layer 1: h1 = relu(obs @ W1 + b1) =================
    {
        const int n0w = wave * 64;
        f32x4 acc[4][4] = {};
        for (int kk = 0; kk < 4; ++kk) {
            const int koff = kk * 32 + l4 * 8;
            bf16x8 afr[4];
#pragma unroll
            for (int mt = 0; mt < 4; ++mt) {
                int row = mt * 16 + l16;
                const float* p = obsG + row * N_OBS + koff;
                f32x4 v0 = *(const f32x4*)(p);
                f32x4 v1 = *(const f32x4*)(p + 4);
                bf16x8 a;
                a[0]=(__bf16)v0.x; a[1]=(__bf16)v0.y; a[2]=(__bf16)v0.z; a[3]=(__bf16)v0.w;
                a[4]=(__bf16)v1.x; a[5]=(__bf16)v1.y; a[6]=(__bf16)v1.z; a[7]=(__bf16)v1.w;
                afr[mt] = a;
            }
#pragma unroll
            for (int nt = 0; nt < 4; ++nt) {
                int col = n0w + nt * 16 + l16;
                bf16x8 bfr = load_bf8_lds(WT1 + (size_t)col * N_OBS + koff);
#pragma unroll
                for (int mt = 0; mt < 4; ++mt)
                    acc[mt][nt] = __builtin_amdgcn_mfma_f32_16x16x32_bf16(afr[mt], bfr, acc[mt][nt], 0, 0, 0);
            }
        }
#pragma unroll
        for (int nt = 0; nt < 4; ++nt) {
            int col = n0w + nt * 16 + l16;
            float bias = b1[col];
#pragma unroll
            for (int mt = 0; mt < 4; ++mt)
#pragma unroll
                for (int i = 0; i < 4; ++i) {
                    int row = mt * 16 + l4 * 4 + i;
                    float v = acc[mt][nt][i] + bias;
                    v = v > 0.f ? v : 0.f;
                    hA[row * 520 + col] = f2bf(v);
                }
        }
    }
    __syncthreads();

    // ================= Layer 2: h2 = relu(h1 @ W2 + b2) =================
    {
        const int n0w = wave * 64;
        f32x4 acc[4][4] = {};
        for (int kk = 0; kk < 16; ++kk) {
            const int koff = kk * 32 + l4 * 8;
            bf16x8 afr[4];
#pragma unroll
            for (int mt = 0; mt < 4; ++mt)
                afr[mt] = load_bf8_lds(hA + (mt * 16 + l16) * 520 + koff);
#pragma unroll
            for (int nt = 0; nt < 4; ++nt) {
                int col = n0w + nt * 16 + l16;
                bf16x8 bfr = load_bf8_lds(WT2 + (size_t)col * N_H1 + koff);
#pragma unroll
                for (int mt = 0; mt < 4; ++mt)
                    acc[mt][nt] = __builtin_amdgcn_mfma_f32_16x16x32_bf16(afr[mt], bfr, acc[mt][nt], 0, 0, 0);
            }
        }
#pragma unroll
        for (int nt = 0; nt < 4; ++nt) {
            int col = n0w + nt * 16 + l16;
            float bias = b2[col];
#pragma unroll
            for (int mt = 0; mt < 4; ++mt)
#pragma unroll
                for (int i = 0; i < 4; ++i) {
                    int row = mt * 16 + l4 * 4 + i;
                    float v = acc[mt][nt][i] + bias;
                    v = v > 0.f ? v : 0.f;
                    hB[row * 520 + col] = f2bf(v);
                }
        }
    }
    __syncthreads();

    // ================= Layer 3: emb = h2 @ W3 + b3 (f32 into embF) =================
    {
        const int n0w = wave * 32;
        f32x4 acc[4][2] = {};
        for (int kk = 0; kk < 16; ++kk) {
            const int koff = kk * 32 + l4 * 8;
            bf16x8 afr[4];
#pragma unroll
            for (int mt = 0; mt < 4; ++mt)
                afr[mt] = load_bf8_lds(hB + (mt * 16 + l16) * 520 + koff);
#pragma unroll
            for (int nt = 0; nt < 2; ++nt) {
                int col = n0w + nt * 16 + l16;
                bf16x8 bfr = load_bf8_lds(WT3 + (size_t)col * N_H2 + koff);
#pragma unroll
                for (int mt = 0; mt < 4; ++mt)
                    acc[mt][nt] = __builtin_amdgcn_mfma_f32_16x16x32_bf16(afr[mt], bfr, acc[mt][nt], 0, 0, 0);
            }
        }
#pragma unroll
        for (int nt = 0; nt < 2; ++nt) {
            int col = n0w + nt * 16 + l16;
            float bias = b3[col];
#pragma unroll
            for (int mt = 0; mt < 4; ++mt)
#pragma unroll
                for (int i = 0; i < 4; ++i) {
                    int row = mt * 16 + l4 * 4 + i;
                    embF[row * 260 + col] = acc[mt][nt][i] + bias;
                }
        }
    }
    __syncthreads();   // all hB reads done; hB region becomes q/s1/s2/mk/tokF

    // ---- stage token queries + mask
    {
#pragma unroll
        for (int r = 0; r < 2; ++r) {
            int i4 = tid + r * 512;          // 1024 float4s
            int row = i4 >> 6, c4 = i4 & 63;
            f32x4 v = *(const f32x4*)(tq + row * 256 + c4 * 4);
            *(f32x4*)(qF + row * 260 + c4 * 4) = v;
        }
        if (tid < 64) mk[tid] = amask[(size_t)bt * 64 + tid];
    }
    __syncthreads();

    // ---- step 1: s1[i][j] = q[i]·emb[j] / 16
    {
#pragma unroll
        for (int r = 0; r < 2; ++r) {
            int p = tid + r * 512;
            int i = p >> 6, j = p & 63;
            const float* er = embF + j * 260;
            const float* qr = qF + i * 260;
            float acc = 0.f;
            for (int d4 = 0; d4 < 64; ++d4) {
                f32x4 e  = *(const f32x4*)(er + d4 * 4);
                f32x4 qq = *(const f32x4*)(qr + d4 * 4);
                acc += e.x*qq.x + e.y*qq.y + e.z*qq.z + e.w*qq.w;
            }
            s1[i * 65 + j] = acc * 0.0625f;
        }
    }
    __syncthreads();

    // ---- step 2: masked softmax over j (rows i), weights back into s1
    if (tid < 256) {
        int i = tid >> 4, g = tid & 15;
        float sv[4]; int ms[4];
        float mx = -3.0e38f;
#pragma unroll
        for (int r = 0; r < 4; ++r) {
            int j = g + r * 16;
            ms[r] = mk[j];
            float s = s1[i * 65 + j];
            sv[r] = ms[r] ? s : -1.0e9f;
            mx = fmaxf(mx, sv[r]);
        }
#pragma unroll
        for (int off = 1; off < 16; off <<= 1) mx = fmaxf(mx, __shfl_xor(mx, off, 16));
        float se = 0.f, ev[4];
#pragma unroll
        for (int r = 0; r < 4; ++r) {
            ev[r] = ms[r] ? __expf(sv[r] - mx) : 0.f;
            se += ev[r];
        }
#pragma unroll
        for (int off = 1; off < 16; off <<= 1) se += __shfl_xor(se, off, 16);
        float inv = 1.0f / fmaxf(se, 1e-8f);
#pragma unroll
        for (int r = 0; r < 4; ++r) s1[i * 65 + (g + r * 16)] = ev[r] * inv;
    }
    __syncthreads();

    // ---- step 3: tokens[i][d] = sum_j w[i][j] emb[j][d]  (also write outT)
    {
        int i  = tid >> 5;           // 0..15
        int dl = (tid & 31) * 4;     // d = dl + c*128
        f32x4 a0 = {0,0,0,0}, a1 = {0,0,0,0};
        for (int j = 0; j < 64; ++j) {
            float w = s1[i * 65 + j];
            f32x4 e0 = *(const f32x4*)(embF + j * 260 + dl);
            f32x4 e1 = *(const f32x4*)(embF + j * 260 + dl + 128);
            a0 += w * e0;
            a1 += w * e1;
        }
        *(f32x4*)(tokF + i * 260 + dl)       = a0;
        *(f32x4*)(tokF + i * 260 + dl + 128) = a1;
        float* op = outT + (size_t)bt * (N_K * N_D) + i * N_D;
        *(f32x4*)(op + dl)       = a0;
        *(f32x4*)(op + dl + 128) = a1;
    }
    __syncthreads();

    // ---- step 4: s2[j][i] = emb[j]·tok[i] / 16
    {
        int jj = tid >> 3;           // 0..63
        int ib = (tid & 7) * 2;      // i, i+1
        const float* er = embF + jj * 260;
        const float* t0 = tokF + ib * 260;
        const float* t1 = tokF + (ib + 1) * 260;
        float a0 = 0.f, a1 = 0.f;
        for (int d4 = 0; d4 < 64; ++d4) {
            f32x4 e = *(const f32x4*)(er + d4 * 4);
            f32x4 u = *(const f32x4*)(t0 + d4 * 4);
            f32x4 v = *(const f32x4*)(t1 + d4 * 4);
            a0 += e.x*u.x + e.y*u.y + e.z*u.z + e.w*u.w;
            a1 += e.x*v.x + e.y*v.y + e.z*v.z + e.w*v.w;
        }
        s2[jj * 17 + ib]     = a0 * 0.0625f;
        s2[jj * 17 + ib + 1] = a1 * 0.0625f;
    }
    __syncthreads();

    // ---- step 5: softmax over i (rows j), no mask
    if (tid < 256) {
        int j = tid >> 2, g = tid & 3;
        float sv[4];
        float mx = -3.0e38f;
#pragma unroll
        for (int r = 0; r < 4; ++r) { sv[r] = s2[j * 17 + g + r * 4]; mx = fmaxf(mx, sv[r]); }
#pragma unroll
        for (int off = 1; off < 4; off <<= 1) mx = fmaxf(mx, __shfl_xor(mx, off, 4));
        float se = 0.f, ev[4];
#pragma unroll
        for (int r = 0; r < 4; ++r) { ev[r] = __expf(sv[r] - mx); se += ev[r]; }
#pragma unroll
        for (int off = 1; off < 4; off <<= 1) se += __shfl_xor(se, off, 4);
        float inv = 1.0f / se;
#pragma unroll
        for (int r = 0; r < 4; ++r) s2[j * 17 + g + r * 4] = ev[r] * inv;
    }
    __syncthreads();

    // ---- step 6: ctx[j][d] = (sum_i w2[j][i] tok[i][d]) * mask[j]
    {
        int j  = tid >> 3;
        int gl = tid & 7;            // d = gl*4 + c*32
        float m = (float)mk[j];
        f32x4 acc[8] = {};
        for (int i = 0; i < 16; ++i) {
            float w = s2[j * 17 + i];
#pragma unroll
            for (int c = 0; c < 8; ++c) {
                f32x4 tv = *(const f32x4*)(tokF + i * 260 + gl * 4 + c * 32);
                acc[c] += w * tv;
            }
        }
        float* op = outC + (size_t)bt * (N_AG * N_D) + j * N_D;
#pragma unroll
        for (int c = 0; c < 8; ++c)
            *(f32x4*)(op + gl * 4 + c * 32) = acc[c] * m;
    }
}

extern "C" void kernel_launch(void* const* d_in, const int* in_sizes, int n_in,
                              void* d_out, int out_size, void* d_ws, size_t ws_size,
                              hipStream_t stream) {
    (void)in_sizes; (void)n_in; (void)out_size; (void)ws_size;
    const float* obs   = (const float*)d_in[0];
    const int*   amask = (const int*)d_in[1];
    const float* W1    = (const float*)d_in[2];
    const float* b1    = (const float*)d_in[3];
    const float* W2    = (const float*)d_in[4];
    const float* b2    = (const float*)d_in[5];
    const float* W3    = (const float*)d_in[6];
    const float* b3    = (const float*)d_in[7];
    const float* tq    = (const float*)d_in[8];

    unsigned short* wt1 = (unsigned short*)d_ws;          // [512][128]
    unsigned short* wt2 = wt1 + 512 * 128;                // [512][512]
    unsigned short* wt3 = wt2 + 512 * 512;                // [256][512]

    float* outT = (float*)d_out;
    float* outC = outT + (size_t)BT_TOTAL * N_K * N_D;

    transpose_bf16_kernel<<<64,  256, 0, stream>>>(W1, wt1, 128, 512, 16);
    transpose_bf16_kernel<<<256, 256, 0, stream>>>(W2, wt2, 512, 512, 16);
    transpose_bf16_kernel<<<128, 256, 0, stream>>>(W3, wt3, 512, 256, 8);
    fused_mlp_attn<<<BT_TOTAL, 512, LDS_BYTES, stream>>>(
        obs, amask, wt1, b1, wt2, b2, wt3, b3, tq, outT, outC);
}